// Round 11
// baseline (123.016 us; speedup 1.0000x reference)
//
#include <hip/hip_runtime.h>
#include <hip/hip_bf16.h>
#include <cstdint>
#include <cstddef>

typedef unsigned short u16;
typedef short bf16x8 __attribute__((ext_vector_type(8)));
typedef float f32x4 __attribute__((ext_vector_type(4)));

typedef __attribute__((address_space(1))) void gvoid;
typedef __attribute__((address_space(3))) void lvoid;

#define DMs   1024
#define DINs  2048
#define LSEQ  1024
#define NST   16
#define RDT   64
#define NXD   96   /* R + 2N */
#define CL    16   /* scan chunk length */
#define NC    64   /* number of chunks */
#define NSTATE (DINs * NST)   /* 32768 */
#define K2    6144 /* split-bf16 GEMM2 K' = 3*2048 */
#define KS2   16   /* GEMM2 K-split */

__device__ __forceinline__ u16 f2bf(float f) {
  uint32_t u = __builtin_bit_cast(uint32_t, f);
  u += 0x7FFFu + ((u >> 16) & 1u);
  return (u16)(u >> 16);
}
__device__ __forceinline__ float bf2f(u16 h) {
  return __builtin_bit_cast(float, (uint32_t)h << 16);
}
__device__ __forceinline__ void gload_lds16(const u16* g, u16* l) {
  __builtin_amdgcn_global_load_lds((gvoid*)g, (lvoid*)l, 16, 0, 0);
}

// ---------------- fused prep: cvt x/W_in/W_out to bf16, W_x to hi/lo b2 ----------------
__device__ __forceinline__ void cvt4(const float* in, u16* out, int j) {
  float4 v = reinterpret_cast<const float4*>(in)[j];
  ushort4 o;
  o.x = f2bf(v.x); o.y = f2bf(v.y); o.z = f2bf(v.z); o.w = f2bf(v.w);
  reinterpret_cast<ushort4*>(out)[j] = o;
}
__global__ __launch_bounds__(256) void k_prep(
    const float* __restrict__ x, const float* __restrict__ Win,
    const float* __restrict__ Wout, const float* __restrict__ Wx,
    u16* __restrict__ x_bf, u16* __restrict__ win_bf,
    u16* __restrict__ wout_bf, u16* __restrict__ b2) {
  int tid = blockIdx.x * 256 + threadIdx.x;
  int stride = gridDim.x * 256;
  for (int j = tid; j < (DMs * LSEQ) / 4; j += stride) cvt4(x, x_bf, j);
  for (int j = tid; j < (2 * DINs * DMs) / 4; j += stride) cvt4(Win, win_bf, j);
  for (int j = tid; j < (DMs * DINs) / 4; j += stride) cvt4(Wout, wout_bf, j);
  for (int j = tid; j < NXD * DINs; j += stride) {
    int c = j >> 11, k = j & 2047;
    float v = Wx[j];
    u16 hi = f2bf(v);
    u16 lo = f2bf(v - bf2f(hi));
    size_t base = (size_t)c * K2;
    b2[base + k] = hi;
    b2[base + DINs + k] = hi;
    b2[base + 2 * DINs + k] = lo;
  }
}

// ---------------- 2-deep double-buffered MFMA GEMM (counted vmcnt), K-split, f32/bf16 out ----------------
// C[ksp][M][N] = A[M][kslice] * B[N][kslice]^T.  Linear LDS [rows][BK], 4 waves 2x2.
// XCD-chunked swizzle: same-n0 blocks colocate on one XCD -> W panel + A matrix L2-resident.
template<int TM, int TN, int BK, int KSPLIT, bool OBF>
__global__ __launch_bounds__(256) void k_gemm_db(
    const u16* __restrict__ A, const u16* __restrict__ B, void* __restrict__ Cv,
    int M, int N, int K) {
  constexpr int WTM = TM / 2, WTN = TN / 2;
  constexpr int FM = WTM / 16, FN = WTN / 16;
  constexpr int KSUB = BK / 32;
  constexpr int LA = TM * BK / 2048, LB = TN * BK / 2048;
  constexpr int TPR = BK / 8;       // threads per staged row
  constexpr int RPR = 256 / TPR;    // rows per staging round
  __shared__ __align__(16) u16 As[2][TM * BK];
  __shared__ __align__(16) u16 Bs[2][TN * BK];
  const int t = threadIdx.x;
  const int lane = t & 63, w = t >> 6;
  // XCD-chunked bijective swizzle (all grids are multiples of 8)
  int nwg = gridDim.x * gridDim.y * gridDim.z;
  int id = blockIdx.x + blockIdx.y * gridDim.x + blockIdx.z * gridDim.x * gridDim.y;
  int lid = (id & 7) * (nwg >> 3) + (id >> 3);
  int bx = lid % gridDim.x;
  int rest = lid / gridDim.x;
  int by = rest % gridDim.y;
  int bz = rest / gridDim.y;
  const int m0 = bx * TM, n0 = by * TN;
  const int kbase = bz * (K / KSPLIT);
  const int wm = (w >> 1) * WTM, wn = (w & 1) * WTN;
  const int fr = lane & 15, g = lane >> 4;
  const int ar = t / TPR, acg = (t % TPR) * 8;
  f32x4 acc[FM][FN] = {};
  const int nt = (K / KSPLIT) / BK;
  auto stage = [&](int buf, int k0) {
#pragma unroll
    for (int i = 0; i < LA; ++i)
      gload_lds16(&A[(size_t)(m0 + ar + i * RPR) * K + k0 + acg], &As[buf][(t + i * 256) * 8]);
#pragma unroll
    for (int i = 0; i < LB; ++i)
      gload_lds16(&B[(size_t)(n0 + ar + i * RPR) * K + k0 + acg], &Bs[buf][(t + i * 256) * 8]);
  };
  stage(0, kbase);
  int cur = 0;
  for (int tt = 0; tt < nt; ++tt) {
    if (tt + 1 < nt) {
      stage(cur ^ 1, kbase + (tt + 1) * BK);
      asm volatile("s_waitcnt vmcnt(%0)" :: "n"(LA + LB) : "memory");
    } else {
      asm volatile("s_waitcnt vmcnt(0)" ::: "memory");
    }
    __builtin_amdgcn_s_barrier();
    bf16x8 af[FM][KSUB], bfv[FN][KSUB];
#pragma unroll
    for (int i = 0; i < FM; ++i)
#pragma unroll
      for (int ks = 0; ks < KSUB; ++ks)
        af[i][ks] = *(const bf16x8*)&As[cur][(wm + i * 16 + fr) * BK + ks * 32 + g * 8];
#pragma unroll
    for (int j = 0; j < FN; ++j)
#pragma unroll
      for (int ks = 0; ks < KSUB; ++ks)
        bfv[j][ks] = *(const bf16x8*)&Bs[cur][(wn + j * 16 + fr) * BK + ks * 32 + g * 8];
#pragma unroll
    for (int ks = 0; ks < KSUB; ++ks)
#pragma unroll
      for (int i = 0; i < FM; ++i)
#pragma unroll
        for (int j = 0; j < FN; ++j)
          acc[i][j] = __builtin_amdgcn_mfma_f32_16x16x32_bf16(af[i][ks], bfv[j][ks], acc[i][j], 0, 0, 0);
    __builtin_amdgcn_s_barrier();
    cur ^= 1;
  }
  // C/D layout: col = lane&15, row = (lane>>4)*4 + reg
#pragma unroll
  for (int i = 0; i < FM; ++i)
#pragma unroll
    for (int j = 0; j < FN; ++j) {
      int mb = m0 + wm + i * 16 + g * 4;
      int nn = n0 + wn + j * 16 + fr;
      if (OBF) {
        u16* Co = (u16*)Cv + (size_t)bz * M * N;
#pragma unroll
        for (int e = 0; e < 4; ++e)
          Co[(size_t)(mb + e) * N + nn] = f2bf(acc[i][j][e]);
      } else {
        float* Co = (float*)Cv + (size_t)bz * M * N;
#pragma unroll
        for (int e = 0; e < 4; ++e)
          Co[(size_t)(mb + e) * N + nn] = acc[i][j][e];
      }
    }
}

// out = p0 + p1 (GEMM4 K-split reduce)
__global__ void k_add2(const float* __restrict__ p, float* __restrict__ out, int n4) {
  int j = blockIdx.x * 256 + threadIdx.x;
  if (j < n4) {
    float4 a = reinterpret_cast<const float4*>(p)[j];
    float4 b = reinterpret_cast<const float4*>(p + (size_t)DMs * LSEQ)[j];
    float4 o; o.x = a.x + b.x; o.y = a.y + b.y; o.z = a.z + b.z; o.w = a.w + b.w;
    reinterpret_cast<float4*>(out)[j] = o;
  }
}

// ---------------- causal depthwise conv (K=4, bf16 in), 4 rows/thread ----------------
__global__ __launch_bounds__(256) void k_conv(
    const u16* __restrict__ xz, const float* __restrict__ cw, const float* __restrict__ cb,
    float* __restrict__ xc, u16* __restrict__ a2) {
  int d = blockIdx.x * 256 + threadIdx.x;
  int l0 = blockIdx.y * 4;
  float4 wv = *(const float4*)&cw[d * 4];
  float bias = cb[d];
  float xm3 = l0 >= 3 ? bf2f(xz[(size_t)(l0 - 3) * (2 * DINs) + d]) : 0.f;
  float xm2 = l0 >= 2 ? bf2f(xz[(size_t)(l0 - 2) * (2 * DINs) + d]) : 0.f;
  float xm1 = l0 >= 1 ? bf2f(xz[(size_t)(l0 - 1) * (2 * DINs) + d]) : 0.f;
#pragma unroll
  for (int li = 0; li < 4; ++li) {
    int l = l0 + li;
    float xcur = bf2f(xz[(size_t)l * (2 * DINs) + d]);
    float acc = bias + wv.x * xm3 + wv.y * xm2 + wv.z * xm1 + wv.w * xcur;
    float sg = 1.f / (1.f + __expf(-acc));
    float v = acc * sg;
    xc[(size_t)l * DINs + d] = v;
    u16 hi = f2bf(v);
    u16 lo = f2bf(v - bf2f(hi));
    size_t base = (size_t)l * K2;
    a2[base + d] = hi;
    a2[base + DINs + d] = lo;
    a2[base + 2 * DINs + d] = hi;
    xm3 = xm2; xm2 = xm1; xm1 = xcur;
  }
}

// ---------------- GEMM2 (split-bf16 MFMA, 2-deep, BK=64, K-split 16): part[ks][L][96] ----------------
__global__ __launch_bounds__(256) void k_gemm2db(
    const u16* __restrict__ A2, const u16* __restrict__ B2, float* __restrict__ part) {
  __shared__ __align__(16) u16 As[2][64 * 64];
  __shared__ __align__(16) u16 Bs[2][96 * 64];
  const int t = threadIdx.x;
  const int lane = t & 63, w = t >> 6;
  // XCD-chunked swizzle (grid 16x16 = 256)
  int id = blockIdx.x + blockIdx.y * 16;
  int lid = (id & 7) * 32 + (id >> 3);
  const int m0 = (lid & 15) * 64;
  const int ks = lid >> 4;
  const int kbeg = ks * (K2 / KS2);
  const int wm = (w >> 1) * 32, wn = (w & 1) * 48;
  const int fr = lane & 15, g = lane >> 4;
  const int ar = t >> 3, acg = (t & 7) * 8;
  f32x4 acc[2][3] = {};
  const int nt = (K2 / KS2) / 64;   // 6
  auto stage = [&](int buf, int k0) {
#pragma unroll
    for (int i = 0; i < 2; ++i)
      gload_lds16(&A2[(size_t)(m0 + ar + i * 32) * K2 + k0 + acg], &As[buf][(t + i * 256) * 8]);
#pragma unroll
    for (int i = 0; i < 3; ++i)
      gload_lds16(&B2[(size_t)(ar + i * 32) * K2 + k0 + acg], &Bs[buf][(t + i * 256) * 8]);
  };
  stage(0, kbeg);
  int cur = 0;
  for (int tt = 0; tt < nt; ++tt) {
    if (tt + 1 < nt) {
      stage(cur ^ 1, kbeg + (tt + 1) * 64);
      asm volatile("s_waitcnt vmcnt(5)" ::: "memory");
    } else {
      asm volatile("s_waitcnt vmcnt(0)" ::: "memory");
    }
    __builtin_amdgcn_s_barrier();
    bf16x8 af[2][2], bfv[3][2];
#pragma unroll
    for (int i = 0; i < 2; ++i)
#pragma unroll
      for (int kk = 0; kk < 2; ++kk)
        af[i][kk] = *(const bf16x8*)&As[cur][(wm + i * 16 + fr) * 64 + kk * 32 + g * 8];
#pragma unroll
    for (int j = 0; j < 3; ++j)
#pragma unroll
      for (int kk = 0; kk < 2; ++kk)
        bfv[j][kk] = *(const bf16x8*)&Bs[cur][(wn + j * 16 + fr) * 64 + kk * 32 + g * 8];
#pragma unroll
    for (int kk = 0; kk < 2; ++kk)
#pragma unroll
      for (int i = 0; i < 2; ++i)
#pragma unroll
        for (int j = 0; j < 3; ++j)
          acc[i][j] = __builtin_amdgcn_mfma_f32_16x16x32_bf16(af[i][kk], bfv[j][kk], acc[i][j], 0, 0, 0);
    __builtin_amdgcn_s_barrier();
    cur ^= 1;
  }
  float* P = part + (size_t)ks * (LSEQ * NXD);
#pragma unroll
  for (int i = 0; i < 2; ++i)
#pragma unroll
    for (int j = 0; j < 3; ++j) {
      int mb = m0 + wm + i * 16 + g * 4;
      int nn = wn + j * 16 + fr;
#pragma unroll
      for (int e = 0; e < 4; ++e)
        P[(size_t)(mb + e) * NXD + nn] = acc[i][j][e];
    }
}

__global__ void k_red(const float* __restrict__ part, float* __restrict__ xdbl) {
  int i = blockIdx.x * 256 + threadIdx.x;
  const int S = LSEQ * NXD;
  float s = 0.f;
#pragma unroll
  for (int k = 0; k < KS2; ++k) s += part[i + (size_t)k * S];
  xdbl[i] = s;
}

// ---------------- Pass A (fused gemm3): dt = softplus(xdbl*W_dt^T + b) -> bf16; chunk-local scan ----------------
__global__ __launch_bounds__(256) void k_scanA(
    const float* __restrict__ xdbl, const float* __restrict__ Wdt,
    const float* __restrict__ bdt, const float* __restrict__ xc,
    const float* __restrict__ Alog,
    float* __restrict__ hout, float* __restrict__ dts, u16* __restrict__ dtf) {
  __shared__ float sX[CL][NXD];   // 16 x 96 f32 = 6 KB
  const int t = threadIdx.x;
  const int d = blockIdx.x * 256 + t;
  const int c = blockIdx.y;
#pragma unroll
  for (int i = 0; i < (CL * NXD) / 256; ++i) {   // 6
    int idx = t + i * 256;
    int l = idx / NXD, cc = idx % NXD;
    sX[l][cc] = xdbl[(size_t)(c * CL + l) * NXD + cc];
  }
  __syncthreads();
  float wreg[64];
#pragma unroll
  for (int i = 0; i < 16; ++i)
    *(float4*)&wreg[i * 4] = *(const float4*)&Wdt[(size_t)d * RDT + i * 4];
  const float bv = bdt[d];
  float ac[NST];
#pragma unroll
  for (int i = 0; i < 4; ++i) {
    float4 v = *(const float4*)&Alog[(size_t)d * NST + i * 4];
    ac[i * 4 + 0] = -__expf(v.x); ac[i * 4 + 1] = -__expf(v.y);
    ac[i * 4 + 2] = -__expf(v.z); ac[i * 4 + 3] = -__expf(v.w);
  }
  float h[NST] = {};
  float dtsum = 0.f;
  for (int l = 0; l < CL; ++l) {
    float d0 = bv, d1 = 0.f, d2 = 0.f, d3 = 0.f;
#pragma unroll
    for (int i = 0; i < 64; i += 4) {
      d0 += sX[l][i]     * wreg[i];
      d1 += sX[l][i + 1] * wreg[i + 1];
      d2 += sX[l][i + 2] * wreg[i + 2];
      d3 += sX[l][i + 3] * wreg[i + 3];
    }
    float accd = (d0 + d1) + (d2 + d3);
    float sp = accd > 20.f ? accd : logf(1.f + __expf(accd));
    u16 dbf = f2bf(sp);
    dtf[(size_t)(c * CL + l) * DINs + d] = dbf;
    float dtv = bf2f(dbf);
    float xcv = xc[(size_t)(c * CL + l) * DINs + d];
    dtsum += dtv;
    float dx = dtv * xcv;
#pragma unroll
    for (int n = 0; n < NST; ++n) {
      float ab = __expf(dtv * ac[n]);
      h[n] = ab * h[n] + dx * sX[l][RDT + n];
    }
  }
  size_t base = (size_t)c * NSTATE + (size_t)d * NST;
#pragma unroll
  for (int n = 0; n < NST; ++n) hout[base + n] = h[n];
  dts[(size_t)c * DINs + d] = dtsum;
}

// ---------------- Pass B: combine chunk summaries -> hpref (64-thr blocks) ----------------
__global__ __launch_bounds__(64) void k_scanB(
    const float* __restrict__ dts, const float* __restrict__ Alog,
    const float* __restrict__ hout, float* __restrict__ hpref) {
  int s = blockIdx.x * 64 + threadIdx.x;   // 0..NSTATE-1; d = s>>4
  const float ac = -__expf(Alog[s]);
  float h = 0.f;
#pragma unroll 8
  for (int c = 0; c < NC; ++c) {
    size_t idx = (size_t)c * NSTATE + s;
    float a = __expf(dts[(size_t)c * DINs + (s >> 4)] * ac);
    float b = hout[idx];
    hpref[idx] = h;
    h = a * h + b;
  }
}

// ---------------- Pass C: recompute with true h_in, fuse y + D*xc + silu(z) gate ----------------
__global__ __launch_bounds__(256) void k_scanC(
    const u16* __restrict__ dtf, const float* __restrict__ xdbl,
    const float* __restrict__ xc, const u16* __restrict__ xz,
    const float* __restrict__ Alog, const float* __restrict__ Dp,
    const float* __restrict__ hpref, u16* __restrict__ ybar) {
  __shared__ float sB[CL][NST], sC[CL][NST];
  const int t = threadIdx.x;
  const int d = blockIdx.x * 256 + t;
  const int c = blockIdx.y;
  {
    int l = t >> 4, n = t & 15;
    sB[l][n] = xdbl[(size_t)(c * CL + l) * NXD + RDT + n];
    sC[l][n] = xdbl[(size_t)(c * CL + l) * NXD + RDT + NST + n];
  }
  __syncthreads();
  float ac[NST];
#pragma unroll
  for (int i = 0; i < 4; ++i) {
    float4 v = *(const float4*)&Alog[(size_t)d * NST + i * 4];
    ac[i * 4 + 0] = -__expf(v.x); ac[i * 4 + 1] = -__expf(v.y);
    ac[i * 4 + 2] = -__expf(v.z); ac[i * 4 + 3] = -__expf(v.w);
  }
  float h[NST];
  size_t base = (size_t)c * NSTATE + (size_t)d * NST;
#pragma unroll
  for (int i = 0; i < 4; ++i)
    *(float4*)&h[i * 4] = *(const float4*)&hpref[base + i * 4];
  const float Dv = Dp[d];
#pragma unroll 4
  for (int l = 0; l < CL; ++l) {
    size_t row = (size_t)(c * CL + l);
    float dtv = bf2f(dtf[row * DINs + d]);
    float xcv = xc[row * DINs + d];
    float zv  = bf2f(xz[row * (2 * DINs) + DINs + d]);
    float dx = dtv * xcv;
    float y0 = Dv * xcv, y1 = 0.f, y2 = 0.f, y3 = 0.f;
#pragma unroll
    for (int n = 0; n < NST; n += 4) {
      float ab0 = __expf(dtv * ac[n]);
      float ab1 = __expf(dtv * ac[n + 1]);
      float ab2 = __expf(dtv * ac[n + 2]);
      float ab3 = __expf(dtv * ac[n + 3]);
      h[n]     = ab0 * h[n]     + dx * sB[l][n];
      h[n + 1] = ab1 * h[n + 1] + dx * sB[l][n + 1];
      h[n + 2] = ab2 * h[n + 2] + dx * sB[l][n + 2];
      h[n + 3] = ab3 * h[n + 3] + dx * sB[l][n + 3];
      y0 += h[n] * sC[l][n];
      y1 += h[n + 1] * sC[l][n + 1];
      y2 += h[n + 2] * sC[l][n + 2];
      y3 += h[n + 3] * sC[l][n + 3];
    }
    float y = (y0 + y1) + (y2 + y3);
    float sz = zv / (1.f + __expf(-zv));
    ybar[row * DINs + d] = f2bf(y * sz);
  }
}

// ---------------- launch ----------------
extern "C" void kernel_launch(void* const* d_in, const int* in_sizes, int n_in,
                              void* d_out, int out_size, void* d_ws, size_t ws_size,
                              hipStream_t stream) {
  (void)in_sizes; (void)n_in; (void)out_size; (void)ws_size;
  const float* x      = (const float*)d_in[0];
  const float* W_in   = (const float*)d_in[1];
  const float* conv_w = (const float*)d_in[2];
  const float* conv_b = (const float*)d_in[3];
  const float* W_x    = (const float*)d_in[4];
  const float* W_dt   = (const float*)d_in[5];
  const float* b_dt   = (const float*)d_in[6];
  const float* A_log  = (const float*)d_in[7];
  const float* D_par  = (const float*)d_in[8];
  const float* W_out  = (const float*)d_in[9];
  float* out = (float*)d_out;

  const size_t MB = 1u << 20;
  char* wsb = (char*)d_ws;
  u16*   x_bf    = (u16*)(wsb + 0);          // 2 MB   (dead after GEMM1)
  u16*   win_bf  = (u16*)(wsb + 2 * MB);     // 8 MB   (dead after GEMM1)
  u16*   a2      = (u16*)(wsb + 0);          // 12 MB  (written by conv, AFTER GEMM1)
  u16*   wout_bf = (u16*)(wsb + 12 * MB);    // 4 MB
  u16*   xz_bf   = (u16*)(wsb + 16 * MB);    // 8 MB (bf16)
  u16*   b2      = (u16*)(wsb + 25 * MB);    // 1.2 MB (2 MB slot)
  float* part    = (float*)(wsb + 27 * MB);  // 6 MB (KS2=16)
  float* xdbl    = (float*)(wsb + 33 * MB);  // 384 KB
  u16*   dtf     = (u16*)(wsb + 34 * MB);    // 4 MB (bf16)
  u16*   ybar    = (u16*)(wsb + 38 * MB);    // 4 MB
  float* hout    = (float*)(wsb + 42 * MB);  // 8 MB (NC=64)
  float* hpref   = (float*)(wsb + 50 * MB);  // 8 MB
  float* dts     = (float*)(wsb + 58 * MB);  // 512 KB
  float* xc      = (float*)(wsb + 59 * MB);  // 8 MB (f32)
  float* g4p     = (float*)(wsb + 67 * MB);  // 8 MB -> total 75 MB

  k_prep<<<1024, 256, 0, stream>>>(x, W_in, W_out, W_x, x_bf, win_bf, wout_bf, b2);

  // GEMM1: xz_bf[L][4096] = x * W_in^T  (bf16 out; 128x128 tile, grid 8x32, XCD-swizzled)
  k_gemm_db<128, 128, 64, 1, true><<<dim3(LSEQ / 128, (2 * DINs) / 128, 1), 256, 0, stream>>>(
      x_bf, win_bf, xz_bf, LSEQ, 2 * DINs, DMs);

  // conv: 4 rows/thread, grid (8, 256) = 2048 blocks
  k_conv<<<dim3(DINs / 256, LSEQ / 4), 256, 0, stream>>>(xz_bf, conv_w, conv_b, xc, a2);

  // GEMM2: split-bf16 MFMA, K' = 6144, K-split 16 (grid 16x16, XCD-swizzled)
  k_gemm2db<<<dim3(LSEQ / 64, KS2), 256, 0, stream>>>(a2, b2, part);
  k_red<<<(LSEQ * NXD) / 256, 256, 0, stream>>>(part, xdbl);

  // chunked scan (CL=16, NC=64; scanA fuses gemm3 with 4-acc dot)
  k_scanA<<<dim3(DINs / 256, NC), 256, 0, stream>>>(xdbl, W_dt, b_dt, xc, A_log,
                                                    hout, dts, dtf);
  k_scanB<<<NSTATE / 64, 64, 0, stream>>>(dts, A_log, hout, hpref);
  k_scanC<<<dim3(DINs / 256, NC), 256, 0, stream>>>(dtf, xdbl, xc, xz_bf, A_log, D_par,
                                                    hpref, ybar);

  // GEMM4: out = ybar * W_out^T   (grid 16x16x2 K-split, XCD-swizzled) + reduce
  k_gemm_db<64, 64, 64, 2, false><<<dim3(LSEQ / 64, DMs / 64, 2), 256, 0, stream>>>(
      ybar, wout_bf, g4p, LSEQ, DMs, DINs);
  k_add2<<<(DMs * LSEQ / 4) / 256, 256, 0, stream>>>(g4p, out, (DMs * LSEQ) / 4);
}

// Round 12
// 115.763 us; speedup vs baseline: 1.0627x; 1.0627x over previous
//
#include <hip/hip_runtime.h>
#include <hip/hip_bf16.h>
#include <cstdint>
#include <cstddef>

typedef unsigned short u16;
typedef short bf16x8 __attribute__((ext_vector_type(8)));
typedef float f32x4 __attribute__((ext_vector_type(4)));

typedef __attribute__((address_space(1))) void gvoid;
typedef __attribute__((address_space(3))) void lvoid;

#define DMs   1024
#define DINs  2048
#define LSEQ  1024
#define NST   16
#define RDT   64
#define NXD   96   /* R + 2N */
#define CL    16   /* scan chunk length */
#define NC    64   /* number of chunks */
#define NSTATE (DINs * NST)   /* 32768 */
#define K2    6144 /* split-bf16 GEMM2 K' = 3*2048 */
#define KS2   16   /* GEMM2 K-split */

__device__ __forceinline__ u16 f2bf(float f) {
  uint32_t u = __builtin_bit_cast(uint32_t, f);
  u += 0x7FFFu + ((u >> 16) & 1u);
  return (u16)(u >> 16);
}
__device__ __forceinline__ float bf2f(u16 h) {
  return __builtin_bit_cast(float, (uint32_t)h << 16);
}
__device__ __forceinline__ void gload_lds16(const u16* g, u16* l) {
  __builtin_amdgcn_global_load_lds((gvoid*)g, (lvoid*)l, 16, 0, 0);
}

// ---------------- fused prep: cvt x/W_in/W_out to bf16, W_x to hi/lo b2 ----------------
__device__ __forceinline__ void cvt4(const float* in, u16* out, int j) {
  float4 v = reinterpret_cast<const float4*>(in)[j];
  ushort4 o;
  o.x = f2bf(v.x); o.y = f2bf(v.y); o.z = f2bf(v.z); o.w = f2bf(v.w);
  reinterpret_cast<ushort4*>(out)[j] = o;
}
__global__ __launch_bounds__(256) void k_prep(
    const float* __restrict__ x, const float* __restrict__ Win,
    const float* __restrict__ Wout, const float* __restrict__ Wx,
    u16* __restrict__ x_bf, u16* __restrict__ win_bf,
    u16* __restrict__ wout_bf, u16* __restrict__ b2) {
  int tid = blockIdx.x * 256 + threadIdx.x;
  int stride = gridDim.x * 256;
  for (int j = tid; j < (DMs * LSEQ) / 4; j += stride) cvt4(x, x_bf, j);
  for (int j = tid; j < (2 * DINs * DMs) / 4; j += stride) cvt4(Win, win_bf, j);
  for (int j = tid; j < (DMs * DINs) / 4; j += stride) cvt4(Wout, wout_bf, j);
  for (int j = tid; j < NXD * DINs; j += stride) {
    int c = j >> 11, k = j & 2047;
    float v = Wx[j];
    u16 hi = f2bf(v);
    u16 lo = f2bf(v - bf2f(hi));
    size_t base = (size_t)c * K2;
    b2[base + k] = hi;
    b2[base + DINs + k] = hi;
    b2[base + 2 * DINs + k] = lo;
  }
}

// ---------------- 2-deep double-buffered MFMA GEMM (counted vmcnt), K-split, f32/bf16 out ----------------
// C[ksp][M][N] = A[M][kslice] * B[N][kslice]^T.  Linear LDS [rows][BK], 4 waves 2x2.  (R10-proven)
template<int TM, int TN, int BK, int KSPLIT, bool OBF>
__global__ __launch_bounds__(256) void k_gemm_db(
    const u16* __restrict__ A, const u16* __restrict__ B, void* __restrict__ Cv,
    int M, int N, int K) {
  constexpr int WTM = TM / 2, WTN = TN / 2;
  constexpr int FM = WTM / 16, FN = WTN / 16;
  constexpr int KSUB = BK / 32;
  constexpr int LA = TM * BK / 2048, LB = TN * BK / 2048;
  constexpr int TPR = BK / 8;       // threads per staged row
  constexpr int RPR = 256 / TPR;    // rows per staging round
  __shared__ __align__(16) u16 As[2][TM * BK];
  __shared__ __align__(16) u16 Bs[2][TN * BK];
  const int t = threadIdx.x;
  const int lane = t & 63, w = t >> 6;
  const int m0 = blockIdx.x * TM, n0 = blockIdx.y * TN;
  const int kbase = blockIdx.z * (K / KSPLIT);
  const int wm = (w >> 1) * WTM, wn = (w & 1) * WTN;
  const int fr = lane & 15, g = lane >> 4;
  const int ar = t / TPR, acg = (t % TPR) * 8;
  f32x4 acc[FM][FN] = {};
  const int nt = (K / KSPLIT) / BK;
  auto stage = [&](int buf, int k0) {
#pragma unroll
    for (int i = 0; i < LA; ++i)
      gload_lds16(&A[(size_t)(m0 + ar + i * RPR) * K + k0 + acg], &As[buf][(t + i * 256) * 8]);
#pragma unroll
    for (int i = 0; i < LB; ++i)
      gload_lds16(&B[(size_t)(n0 + ar + i * RPR) * K + k0 + acg], &Bs[buf][(t + i * 256) * 8]);
  };
  stage(0, kbase);
  int cur = 0;
  for (int tt = 0; tt < nt; ++tt) {
    if (tt + 1 < nt) {
      stage(cur ^ 1, kbase + (tt + 1) * BK);
      asm volatile("s_waitcnt vmcnt(%0)" :: "n"(LA + LB) : "memory");
    } else {
      asm volatile("s_waitcnt vmcnt(0)" ::: "memory");
    }
    __builtin_amdgcn_s_barrier();
    bf16x8 af[FM][KSUB], bfv[FN][KSUB];
#pragma unroll
    for (int i = 0; i < FM; ++i)
#pragma unroll
      for (int ks = 0; ks < KSUB; ++ks)
        af[i][ks] = *(const bf16x8*)&As[cur][(wm + i * 16 + fr) * BK + ks * 32 + g * 8];
#pragma unroll
    for (int j = 0; j < FN; ++j)
#pragma unroll
      for (int ks = 0; ks < KSUB; ++ks)
        bfv[j][ks] = *(const bf16x8*)&Bs[cur][(wn + j * 16 + fr) * BK + ks * 32 + g * 8];
#pragma unroll
    for (int ks = 0; ks < KSUB; ++ks)
#pragma unroll
      for (int i = 0; i < FM; ++i)
#pragma unroll
        for (int j = 0; j < FN; ++j)
          acc[i][j] = __builtin_amdgcn_mfma_f32_16x16x32_bf16(af[i][ks], bfv[j][ks], acc[i][j], 0, 0, 0);
    __builtin_amdgcn_s_barrier();
    cur ^= 1;
  }
  // C/D layout: col = lane&15, row = (lane>>4)*4 + reg
#pragma unroll
  for (int i = 0; i < FM; ++i)
#pragma unroll
    for (int j = 0; j < FN; ++j) {
      int mb = m0 + wm + i * 16 + g * 4;
      int nn = n0 + wn + j * 16 + fr;
      if (OBF) {
        u16* Co = (u16*)Cv + (size_t)blockIdx.z * M * N;
#pragma unroll
        for (int e = 0; e < 4; ++e)
          Co[(size_t)(mb + e) * N + nn] = f2bf(acc[i][j][e]);
      } else {
        float* Co = (float*)Cv + (size_t)blockIdx.z * M * N;
#pragma unroll
        for (int e = 0; e < 4; ++e)
          Co[(size_t)(mb + e) * N + nn] = acc[i][j][e];
      }
    }
}

// out = p0 + p1 (GEMM4 K-split reduce)
__global__ void k_add2(const float* __restrict__ p, float* __restrict__ out, int n4) {
  int j = blockIdx.x * 256 + threadIdx.x;
  if (j < n4) {
    float4 a = reinterpret_cast<const float4*>(p)[j];
    float4 b = reinterpret_cast<const float4*>(p + (size_t)DMs * LSEQ)[j];
    float4 o; o.x = a.x + b.x; o.y = a.y + b.y; o.z = a.z + b.z; o.w = a.w + b.w;
    reinterpret_cast<float4*>(out)[j] = o;
  }
}

// ---------------- causal depthwise conv (K=4, bf16 in), 4 rows/thread ----------------
__global__ __launch_bounds__(256) void k_conv(
    const u16* __restrict__ xz, const float* __restrict__ cw, const float* __restrict__ cb,
    float* __restrict__ xc, u16* __restrict__ a2) {
  int d = blockIdx.x * 256 + threadIdx.x;
  int l0 = blockIdx.y * 4;
  float4 wv = *(const float4*)&cw[d * 4];
  float bias = cb[d];
  float xm3 = l0 >= 3 ? bf2f(xz[(size_t)(l0 - 3) * (2 * DINs) + d]) : 0.f;
  float xm2 = l0 >= 2 ? bf2f(xz[(size_t)(l0 - 2) * (2 * DINs) + d]) : 0.f;
  float xm1 = l0 >= 1 ? bf2f(xz[(size_t)(l0 - 1) * (2 * DINs) + d]) : 0.f;
#pragma unroll
  for (int li = 0; li < 4; ++li) {
    int l = l0 + li;
    float xcur = bf2f(xz[(size_t)l * (2 * DINs) + d]);
    float acc = bias + wv.x * xm3 + wv.y * xm2 + wv.z * xm1 + wv.w * xcur;
    float sg = 1.f / (1.f + __expf(-acc));
    float v = acc * sg;
    xc[(size_t)l * DINs + d] = v;
    u16 hi = f2bf(v);
    u16 lo = f2bf(v - bf2f(hi));
    size_t base = (size_t)l * K2;
    a2[base + d] = hi;
    a2[base + DINs + d] = lo;
    a2[base + 2 * DINs + d] = hi;
    xm3 = xm2; xm2 = xm1; xm1 = xcur;
  }
}

// ---------------- GEMM2 (split-bf16 MFMA, 2-deep, BK=64, K-split 16): part[ks][L][96] ----------------
__global__ __launch_bounds__(256) void k_gemm2db(
    const u16* __restrict__ A2, const u16* __restrict__ B2, float* __restrict__ part) {
  __shared__ __align__(16) u16 As[2][64 * 64];
  __shared__ __align__(16) u16 Bs[2][96 * 64];
  const int t = threadIdx.x;
  const int lane = t & 63, w = t >> 6;
  const int m0 = blockIdx.x * 64;
  const int ks = blockIdx.y;
  const int kbeg = ks * (K2 / KS2);
  const int wm = (w >> 1) * 32, wn = (w & 1) * 48;
  const int fr = lane & 15, g = lane >> 4;
  const int ar = t >> 3, acg = (t & 7) * 8;
  f32x4 acc[2][3] = {};
  const int nt = (K2 / KS2) / 64;   // 6
  auto stage = [&](int buf, int k0) {
#pragma unroll
    for (int i = 0; i < 2; ++i)
      gload_lds16(&A2[(size_t)(m0 + ar + i * 32) * K2 + k0 + acg], &As[buf][(t + i * 256) * 8]);
#pragma unroll
    for (int i = 0; i < 3; ++i)
      gload_lds16(&B2[(size_t)(ar + i * 32) * K2 + k0 + acg], &Bs[buf][(t + i * 256) * 8]);
  };
  stage(0, kbeg);
  int cur = 0;
  for (int tt = 0; tt < nt; ++tt) {
    if (tt + 1 < nt) {
      stage(cur ^ 1, kbeg + (tt + 1) * 64);
      asm volatile("s_waitcnt vmcnt(5)" ::: "memory");
    } else {
      asm volatile("s_waitcnt vmcnt(0)" ::: "memory");
    }
    __builtin_amdgcn_s_barrier();
    bf16x8 af[2][2], bfv[3][2];
#pragma unroll
    for (int i = 0; i < 2; ++i)
#pragma unroll
      for (int kk = 0; kk < 2; ++kk)
        af[i][kk] = *(const bf16x8*)&As[cur][(wm + i * 16 + fr) * 64 + kk * 32 + g * 8];
#pragma unroll
    for (int j = 0; j < 3; ++j)
#pragma unroll
      for (int kk = 0; kk < 2; ++kk)
        bfv[j][kk] = *(const bf16x8*)&Bs[cur][(wn + j * 16 + fr) * 64 + kk * 32 + g * 8];
#pragma unroll
    for (int kk = 0; kk < 2; ++kk)
#pragma unroll
      for (int i = 0; i < 2; ++i)
#pragma unroll
        for (int j = 0; j < 3; ++j)
          acc[i][j] = __builtin_amdgcn_mfma_f32_16x16x32_bf16(af[i][kk], bfv[j][kk], acc[i][j], 0, 0, 0);
    __builtin_amdgcn_s_barrier();
    cur ^= 1;
  }
  float* P = part + (size_t)ks * (LSEQ * NXD);
#pragma unroll
  for (int i = 0; i < 2; ++i)
#pragma unroll
    for (int j = 0; j < 3; ++j) {
      int mb = m0 + wm + i * 16 + g * 4;
      int nn = wn + j * 16 + fr;
#pragma unroll
      for (int e = 0; e < 4; ++e)
        P[(size_t)(mb + e) * NXD + nn] = acc[i][j][e];
    }
}

// ---------------- Pass A (fused red + gemm3): sum part slices -> sX; dt; chunk-local scan ----------------
__global__ __launch_bounds__(256) void k_scanA(
    const float* __restrict__ part, const float* __restrict__ Wdt,
    const float* __restrict__ bdt, const float* __restrict__ xc,
    const float* __restrict__ Alog,
    float* __restrict__ hout, float* __restrict__ dts, u16* __restrict__ dtf) {
  __shared__ float sX[CL][NXD];   // 16 x 96 f32 = 6 KB
  const int t = threadIdx.x;
  const int d = blockIdx.x * 256 + t;
  const int c = blockIdx.y;
  const int S = LSEQ * NXD;
#pragma unroll
  for (int i = 0; i < (CL * NXD) / 256; ++i) {   // 6
    int idx = t + i * 256;
    size_t off = (size_t)(c * CL) * NXD + idx;   // rows are contiguous in part slice
    float s = 0.f;
#pragma unroll
    for (int ks = 0; ks < KS2; ++ks) s += part[(size_t)ks * S + off];
    sX[idx / NXD][idx % NXD] = s;
  }
  __syncthreads();
  float wreg[64];
#pragma unroll
  for (int i = 0; i < 16; ++i)
    *(float4*)&wreg[i * 4] = *(const float4*)&Wdt[(size_t)d * RDT + i * 4];
  const float bv = bdt[d];
  float ac[NST];
#pragma unroll
  for (int i = 0; i < 4; ++i) {
    float4 v = *(const float4*)&Alog[(size_t)d * NST + i * 4];
    ac[i * 4 + 0] = -__expf(v.x); ac[i * 4 + 1] = -__expf(v.y);
    ac[i * 4 + 2] = -__expf(v.z); ac[i * 4 + 3] = -__expf(v.w);
  }
  float h[NST] = {};
  float dtsum = 0.f;
  for (int l = 0; l < CL; ++l) {
    float d0 = bv, d1 = 0.f, d2 = 0.f, d3 = 0.f;
#pragma unroll
    for (int i = 0; i < 64; i += 4) {
      d0 += sX[l][i]     * wreg[i];
      d1 += sX[l][i + 1] * wreg[i + 1];
      d2 += sX[l][i + 2] * wreg[i + 2];
      d3 += sX[l][i + 3] * wreg[i + 3];
    }
    float accd = (d0 + d1) + (d2 + d3);
    float sp = accd > 20.f ? accd : logf(1.f + __expf(accd));
    u16 dbf = f2bf(sp);
    dtf[(size_t)(c * CL + l) * DINs + d] = dbf;
    float dtv = bf2f(dbf);
    float xcv = xc[(size_t)(c * CL + l) * DINs + d];
    dtsum += dtv;
    float dx = dtv * xcv;
#pragma unroll
    for (int n = 0; n < NST; ++n) {
      float ab = __expf(dtv * ac[n]);
      h[n] = ab * h[n] + dx * sX[l][RDT + n];
    }
  }
  size_t base = (size_t)c * NSTATE + (size_t)d * NST;
#pragma unroll
  for (int n = 0; n < NST; ++n) hout[base + n] = h[n];
  dts[(size_t)c * DINs + d] = dtsum;
}

// ---------------- Pass B: combine chunk summaries -> hpref (64-thr blocks) ----------------
__global__ __launch_bounds__(64) void k_scanB(
    const float* __restrict__ dts, const float* __restrict__ Alog,
    const float* __restrict__ hout, float* __restrict__ hpref) {
  int s = blockIdx.x * 64 + threadIdx.x;   // 0..NSTATE-1; d = s>>4
  const float ac = -__expf(Alog[s]);
  float h = 0.f;
#pragma unroll 8
  for (int c = 0; c < NC; ++c) {
    size_t idx = (size_t)c * NSTATE + s;
    float a = __expf(dts[(size_t)c * DINs + (s >> 4)] * ac);
    float b = hout[idx];
    hpref[idx] = h;
    h = a * h + b;
  }
}

// ---------------- Pass C (fused red): recompute with true h_in, y + D*xc + silu(z) gate ----------------
__global__ __launch_bounds__(256) void k_scanC(
    const u16* __restrict__ dtf, const float* __restrict__ part,
    const float* __restrict__ xc, const u16* __restrict__ xz,
    const float* __restrict__ Alog, const float* __restrict__ Dp,
    const float* __restrict__ hpref, u16* __restrict__ ybar) {
  __shared__ float sB[CL][NST], sC[CL][NST];
  const int t = threadIdx.x;
  const int d = blockIdx.x * 256 + t;
  const int c = blockIdx.y;
  const int S = LSEQ * NXD;
#pragma unroll
  for (int i = 0; i < (CL * 2 * NST) / 256; ++i) {   // 2: 512 B/C elements
    int idx = t + i * 256;
    int l = idx >> 5, n = idx & 31;
    size_t off = (size_t)(c * CL + l) * NXD + RDT + n;
    float s = 0.f;
#pragma unroll
    for (int ks = 0; ks < KS2; ++ks) s += part[(size_t)ks * S + off];
    if (n < NST) sB[l][n] = s; else sC[l][n - NST] = s;
  }
  __syncthreads();
  float ac[NST];
#pragma unroll
  for (int i = 0; i < 4; ++i) {
    float4 v = *(const float4*)&Alog[(size_t)d * NST + i * 4];
    ac[i * 4 + 0] = -__expf(v.x); ac[i * 4 + 1] = -__expf(v.y);
    ac[i * 4 + 2] = -__expf(v.z); ac[i * 4 + 3] = -__expf(v.w);
  }
  float h[NST];
  size_t base = (size_t)c * NSTATE + (size_t)d * NST;
#pragma unroll
  for (int i = 0; i < 4; ++i)
    *(float4*)&h[i * 4] = *(const float4*)&hpref[base + i * 4];
  const float Dv = Dp[d];
#pragma unroll 4
  for (int l = 0; l < CL; ++l) {
    size_t row = (size_t)(c * CL + l);
    float dtv = bf2f(dtf[row * DINs + d]);
    float xcv = xc[row * DINs + d];
    float zv  = bf2f(xz[row * (2 * DINs) + DINs + d]);
    float dx = dtv * xcv;
    float y0 = Dv * xcv, y1 = 0.f, y2 = 0.f, y3 = 0.f;
#pragma unroll
    for (int n = 0; n < NST; n += 4) {
      float ab0 = __expf(dtv * ac[n]);
      float ab1 = __expf(dtv * ac[n + 1]);
      float ab2 = __expf(dtv * ac[n + 2]);
      float ab3 = __expf(dtv * ac[n + 3]);
      h[n]     = ab0 * h[n]     + dx * sB[l][n];
      h[n + 1] = ab1 * h[n + 1] + dx * sB[l][n + 1];
      h[n + 2] = ab2 * h[n + 2] + dx * sB[l][n + 2];
      h[n + 3] = ab3 * h[n + 3] + dx * sB[l][n + 3];
      y0 += h[n] * sC[l][n];
      y1 += h[n + 1] * sC[l][n + 1];
      y2 += h[n + 2] * sC[l][n + 2];
      y3 += h[n + 3] * sC[l][n + 3];
    }
    float y = (y0 + y1) + (y2 + y3);
    float sz = zv / (1.f + __expf(-zv));
    ybar[row * DINs + d] = f2bf(y * sz);
  }
}

// ---------------- launch ----------------
extern "C" void kernel_launch(void* const* d_in, const int* in_sizes, int n_in,
                              void* d_out, int out_size, void* d_ws, size_t ws_size,
                              hipStream_t stream) {
  (void)in_sizes; (void)n_in; (void)out_size; (void)ws_size;
  const float* x      = (const float*)d_in[0];
  const float* W_in   = (const float*)d_in[1];
  const float* conv_w = (const float*)d_in[2];
  const float* conv_b = (const float*)d_in[3];
  const float* W_x    = (const float*)d_in[4];
  const float* W_dt   = (const float*)d_in[5];
  const float* b_dt   = (const float*)d_in[6];
  const float* A_log  = (const float*)d_in[7];
  const float* D_par  = (const float*)d_in[8];
  const float* W_out  = (const float*)d_in[9];
  float* out = (float*)d_out;

  const size_t MB = 1u << 20;
  char* wsb = (char*)d_ws;
  u16*   x_bf    = (u16*)(wsb + 0);          // 2 MB   (dead after GEMM1)
  u16*   win_bf  = (u16*)(wsb + 2 * MB);     // 8 MB   (dead after GEMM1)
  u16*   a2      = (u16*)(wsb + 0);          // 12 MB  (written by conv, AFTER GEMM1)
  u16*   wout_bf = (u16*)(wsb + 12 * MB);    // 4 MB
  u16*   xz_bf   = (u16*)(wsb + 16 * MB);    // 8 MB (bf16)
  u16*   b2      = (u16*)(wsb + 25 * MB);    // 1.2 MB (2 MB slot)
  float* part    = (float*)(wsb + 27 * MB);  // 6 MB (KS2=16)
  u16*   dtf     = (u16*)(wsb + 34 * MB);    // 4 MB (bf16)
  u16*   ybar    = (u16*)(wsb + 38 * MB);    // 4 MB
  float* hout    = (float*)(wsb + 42 * MB);  // 8 MB (NC=64)
  float* hpref   = (float*)(wsb + 50 * MB);  // 8 MB
  float* dts     = (float*)(wsb + 58 * MB);  // 512 KB
  float* xc      = (float*)(wsb + 59 * MB);  // 8 MB (f32)
  float* g4p     = (float*)(wsb + 67 * MB);  // 8 MB -> total 75 MB

  k_prep<<<1024, 256, 0, stream>>>(x, W_in, W_out, W_x, x_bf, win_bf, wout_bf, b2);

  // GEMM1: xz_bf[L][4096] = x * W_in^T  (bf16 out; grid 16x32, BK=64, 2-deep)
  k_gemm_db<64, 128, 64, 1, true><<<dim3(LSEQ / 64, (2 * DINs) / 128, 1), 256, 0, stream>>>(
      x_bf, win_bf, xz_bf, LSEQ, 2 * DINs, DMs);

  // conv: 4 rows/thread, grid (8, 256) = 2048 blocks
  k_conv<<<dim3(DINs / 256, LSEQ / 4), 256, 0, stream>>>(xz_bf, conv_w, conv_b, xc, a2);

  // GEMM2: split-bf16 MFMA, K' = 6144, K-split 16 (grid 16x16 = 256 blocks, 6 iters)
  k_gemm2db<<<dim3(LSEQ / 64, KS2), 256, 0, stream>>>(a2, b2, part);

  // chunked scan (CL=16, NC=64; scanA fuses red+gemm3; scanC fuses red)
  k_scanA<<<dim3(DINs / 256, NC), 256, 0, stream>>>(part, W_dt, b_dt, xc, A_log,
                                                    hout, dts, dtf);
  k_scanB<<<NSTATE / 64, 64, 0, stream>>>(dts, A_log, hout, hpref);
  k_scanC<<<dim3(DINs / 256, NC), 256, 0, stream>>>(dtf, part, xc, xz_bf, A_log, D_par,
                                                    hpref, ybar);

  // GEMM4: out = ybar * W_out^T   (grid 16x16x2 K-split, 2-deep) + reduce
  k_gemm_db<64, 64, 64, 2, false><<<dim3(LSEQ / 64, DMs / 64, 2), 256, 0, stream>>>(
      ybar, wout_bf, g4p, LSEQ, DMs, DINs);
  k_add2<<<(DMs * LSEQ / 4) / 256, 256, 0, stream>>>(g4p, out, (DMs * LSEQ) / 4);
}